// Round 1
// baseline (994.529 us; speedup 1.0000x reference)
//
#include <hip/hip_runtime.h>
#include <math.h>

#define EMB_D 64
#define EMB_K 1024
#define NROWS 65536            // 64*32*32
#define QELEMS (NROWS * EMB_D) // 4194304

// d_out layout (floats): [0, 4194304) quantized | [4194304] loss | [4194305, 4259841) indices (as float)
// d_ws layout (bytes):   [0, 262144) Et float[1024][64] | [262144, 266240) esq float[1024]
//                        [266240, 266248) double loss accumulator

// ---------------- Kernel A: transpose codebook, per-code ||e||^2, zero loss accum ----------------
__global__ __launch_bounds__(256) void prep_kernel(const float* __restrict__ E,
                                                   float* __restrict__ Et,
                                                   float* __restrict__ esq,
                                                   double* lsum) {
    int k = blockIdx.x * 256 + threadIdx.x;
    if (k == 0) *lsum = 0.0;  // ws is re-poisoned 0xAA before every launch
    if (k >= EMB_K) return;
    float s = 0.f;
#pragma unroll
    for (int d = 0; d < EMB_D; ++d) {
        float v = E[d * EMB_K + k];       // coalesced read across k
        Et[k * EMB_D + d] = v;            // contiguous per-thread write
        s = fmaf(v, v, s);
    }
    esq[k] = s;
}

// ---------------- Kernel B: per-row argmin over 1024 codes ----------------
// One lane per row: row's 64 floats live in VGPRs; the code vectors are
// wave-uniform loads (expect s_load). Argmin is lane-local (no cross-lane ops).
__global__ __launch_bounds__(256) void argmin_kernel(const float* __restrict__ X,
                                                     const float* __restrict__ Et,
                                                     const float* __restrict__ esq,
                                                     float* __restrict__ idxf) {
    int row = blockIdx.x * 256 + threadIdx.x;
    const float* xr = X + (size_t)row * EMB_D;

    float xv[EMB_D];
#pragma unroll
    for (int i = 0; i < EMB_D / 4; ++i) {
        float4 t = reinterpret_cast<const float4*>(xr)[i];
        xv[4 * i + 0] = t.x; xv[4 * i + 1] = t.y;
        xv[4 * i + 2] = t.z; xv[4 * i + 3] = t.w;
    }
    float xsq = 0.f;
#pragma unroll
    for (int i = 0; i < EMB_D; ++i) xsq = fmaf(xv[i], xv[i], xsq);

    float bestd = INFINITY;
    int besti = 0;
    for (int k = 0; k < EMB_K; k += 2) {   // 2 independent FMA chains for ILP
        const float* e0 = Et + (size_t)k * EMB_D;
        float d0 = 0.f, d1 = 0.f;
#pragma unroll
        for (int i = 0; i < EMB_D; ++i) {
            d0 = fmaf(xv[i], e0[i], d0);
            d1 = fmaf(xv[i], e0[EMB_D + i], d1);
        }
        // replicate reference association: (||x||^2 - 2*dot) + ||e||^2
        float dist0 = (xsq - 2.0f * d0) + esq[k];
        float dist1 = (xsq - 2.0f * d1) + esq[k + 1];
        // argmax(-d) == first index achieving min d  -> strict '<' keeps first
        if (dist0 < bestd) { bestd = dist0; besti = k; }
        if (dist1 < bestd) { bestd = dist1; besti = k + 1; }
    }
    idxf[row] = (float)besti;  // indices output region of d_out
}

// ---------------- Kernel C: gather + straight-through + loss partial sums ----------------
// 16 threads per row, float4 per thread -> fully coalesced.
__global__ __launch_bounds__(256) void gather_kernel(const float* __restrict__ X,
                                                     const float* __restrict__ Et,
                                                     const float* __restrict__ idxf,
                                                     float* __restrict__ out,
                                                     double* lsum) {
    int t = blockIdx.x * 256 + threadIdx.x;  // [0, NROWS*16)
    int row = t >> 4;
    int j = (t & 15) << 2;
    int k = (int)idxf[row];
    const float4 q = *reinterpret_cast<const float4*>(Et + (size_t)k * EMB_D + j);
    const float4 x = *reinterpret_cast<const float4*>(X + (size_t)row * EMB_D + j);
    float dx = q.x - x.x, dy = q.y - x.y, dz = q.z - x.z, dw = q.w - x.w;
    // straight-through: out = x + (q - x), matching reference rounding
    float4 o = make_float4(x.x + dx, x.y + dy, x.z + dz, x.w + dw);
    *reinterpret_cast<float4*>(out + (size_t)row * EMB_D + j) = o;

    float ps = dx * dx + dy * dy + dz * dz + dw * dw;
#pragma unroll
    for (int off = 32; off > 0; off >>= 1) ps += __shfl_down(ps, off, 64);
    __shared__ float wsum[4];
    int lane = threadIdx.x & 63, wid = threadIdx.x >> 6;
    if (lane == 0) wsum[wid] = ps;
    __syncthreads();
    if (threadIdx.x == 0) {
        float bs = (wsum[0] + wsum[1]) + (wsum[2] + wsum[3]);
        atomicAdd(lsum, (double)bs);
    }
}

// ---------------- Kernel D: finalize loss ----------------
__global__ void finalize_kernel(const double* lsum, float* loss_out) {
    double m = *lsum / (double)QELEMS;
    *loss_out = (float)(m + 0.25 * m);  // e_latent + BETA * q_latent (same value)
}

extern "C" void kernel_launch(void* const* d_in, const int* in_sizes, int n_in,
                              void* d_out, int out_size, void* d_ws, size_t ws_size,
                              hipStream_t stream) {
    const float* X = (const float*)d_in[0];   // [64,32,32,64] = 4194304 floats
    const float* E = (const float*)d_in[1];   // [64,1024]     = 65536 floats

    float* out = (float*)d_out;
    float* quant = out;                  // [0, 4194304)
    float* loss  = out + QELEMS;         // [4194304]
    float* idxf  = out + QELEMS + 1;     // [4194305, ...)

    char* ws = (char*)d_ws;
    float*  Et   = (float*)(ws);             // 256 KiB
    float*  esq  = (float*)(ws + 262144);    // 4 KiB
    double* lsum = (double*)(ws + 266240);   // 8 B (256-aligned offset)

    prep_kernel<<<4, 256, 0, stream>>>(E, Et, esq, lsum);
    argmin_kernel<<<NROWS / 256, 256, 0, stream>>>(X, Et, esq, idxf);
    gather_kernel<<<(NROWS * 16) / 256, 256, 0, stream>>>(X, Et, idxf, quant, lsum);
    finalize_kernel<<<1, 1, 0, stream>>>(lsum, loss);
}

// Round 2
// 585.883 us; speedup vs baseline: 1.6975x; 1.6975x over previous
//
#include <hip/hip_runtime.h>
#include <math.h>

#define EMB_D 64
#define EMB_K 1024
#define NROWS 65536            // 64*32*32
#define QELEMS (NROWS * EMB_D) // 4194304

// d_out layout (floats): [0, 4194304) quantized | [4194304] loss | [4194305, ...) indices (as float)
// d_ws layout (bytes):   [0, 262144) Et float[1024][64] | [262144, 266240) esq float[1024]
//                        [266240, 266248) double loss accumulator

// ---------------- Kernel A: transpose codebook, per-code ||e||^2, zero loss accum ----------------
__global__ __launch_bounds__(256) void prep_kernel(const float* __restrict__ E,
                                                   float* __restrict__ Et,
                                                   float* __restrict__ esq,
                                                   double* lsum) {
    int k = blockIdx.x * 256 + threadIdx.x;
    if (k == 0) *lsum = 0.0;  // ws is re-poisoned 0xAA before every launch
    if (k >= EMB_K) return;
    float s = 0.f;
#pragma unroll
    for (int d = 0; d < EMB_D; ++d) {
        float v = E[d * EMB_K + k];       // coalesced read across k
        Et[k * EMB_D + d] = v;            // contiguous per-thread write
        s = fmaf(v, v, s);                // same chain order as round-1 (d ascending)
    }
    esq[k] = s;
}

// accumulate 4 products into acc, in x/y/z/w order (matches round-1's i-ascending chain)
#define DOT4(acc, q, e)                                    \
    do {                                                   \
        acc = fmaf((q).x, (e).x, acc);                     \
        acc = fmaf((q).y, (e).y, acc);                     \
        acc = fmaf((q).z, (e).z, acc);                     \
        acc = fmaf((q).w, (e).w, acc);                     \
    } while (0)

// ---------------- Kernel B: fused argmin + quantize + loss ----------------
// Block = 4 waves over the SAME 64 rows; wave w scans codes [w*256, w*256+256).
// Lane-local argmin (bit-identical arithmetic to round-1), LDS combine in
// ascending-w order with strict '<' (preserves first-wins tie-break), then a
// fused coalesced quantize + loss epilogue.
__global__ __launch_bounds__(256, 4) void main_kernel(const float* __restrict__ X,
                                                      const float* __restrict__ Et,
                                                      const float* __restrict__ esq,
                                                      float* __restrict__ quant,
                                                      float* __restrict__ idxf,
                                                      double* lsum) {
    __shared__ float sd[4][64];
    __shared__ int   si[4][64];
    __shared__ int   sidx[64];

    const int lane = threadIdx.x & 63;
    const int w    = threadIdx.x >> 6;
    const int rowbase = blockIdx.x * 64;

    // ---- load this lane's row into 16 explicit float4 registers (guaranteed SROA) ----
    const float4* xr = reinterpret_cast<const float4*>(X + (size_t)(rowbase + lane) * EMB_D);
    float4 x0 = xr[0],  x1 = xr[1],  x2 = xr[2],  x3 = xr[3];
    float4 x4 = xr[4],  x5 = xr[5],  x6 = xr[6],  x7 = xr[7];
    float4 x8 = xr[8],  x9 = xr[9],  x10 = xr[10], x11 = xr[11];
    float4 x12 = xr[12], x13 = xr[13], x14 = xr[14], x15 = xr[15];

    float xsq = 0.f;
    DOT4(xsq, x0, x0);   DOT4(xsq, x1, x1);   DOT4(xsq, x2, x2);   DOT4(xsq, x3, x3);
    DOT4(xsq, x4, x4);   DOT4(xsq, x5, x5);   DOT4(xsq, x6, x6);   DOT4(xsq, x7, x7);
    DOT4(xsq, x8, x8);   DOT4(xsq, x9, x9);   DOT4(xsq, x10, x10); DOT4(xsq, x11, x11);
    DOT4(xsq, x12, x12); DOT4(xsq, x13, x13); DOT4(xsq, x14, x14); DOT4(xsq, x15, x15);

    float bestd = INFINITY;
    int   besti = 0;
    const int k0 = w * (EMB_K / 4);
    for (int k = k0; k < k0 + EMB_K / 4; k += 2) {   // 2 codes in flight (2 FMA chains)
        const float4* e0 = reinterpret_cast<const float4*>(Et + (size_t)k * EMB_D);
        const float4* e1 = e0 + 16;
        float d0 = 0.f, d1 = 0.f;
#define STEP(i) { float4 a = e0[i]; float4 b = e1[i]; DOT4(d0, x##i, a); DOT4(d1, x##i, b); }
        STEP(0)  STEP(1)  STEP(2)  STEP(3)
        STEP(4)  STEP(5)  STEP(6)  STEP(7)
        STEP(8)  STEP(9)  STEP(10) STEP(11)
        STEP(12) STEP(13) STEP(14) STEP(15)
#undef STEP
        float dist0 = (xsq - 2.0f * d0) + esq[k];
        float dist1 = (xsq - 2.0f * d1) + esq[k + 1];
        if (dist0 < bestd) { bestd = dist0; besti = k; }
        if (dist1 < bestd) { bestd = dist1; besti = k + 1; }
    }
    sd[w][lane] = bestd;
    si[w][lane] = besti;
    __syncthreads();

    // ---- combine the 4 k-chunks (ascending w keeps lowest index on ties) ----
    if (threadIdx.x < 64) {
        float bd = sd[0][lane];
        int   bi = si[0][lane];
#pragma unroll
        for (int u = 1; u < 4; ++u) {
            if (sd[u][lane] < bd) { bd = sd[u][lane]; bi = si[u][lane]; }
        }
        sidx[lane] = bi;
        idxf[rowbase + lane] = (float)bi;
    }
    __syncthreads();

    // ---- fused quantize + loss: thread t handles row t>>2, quarter t&3 (coalesced) ----
    {
        const int r = threadIdx.x >> 2;
        const int p = threadIdx.x & 3;
        const int k = sidx[r];
        const float4* xq = reinterpret_cast<const float4*>(X + (size_t)(rowbase + r) * EMB_D) + p * 4;
        const float4* qq = reinterpret_cast<const float4*>(Et + (size_t)k * EMB_D) + p * 4;
        float4*       oq = reinterpret_cast<float4*>(quant + (size_t)(rowbase + r) * EMB_D) + p * 4;
        float ps = 0.f;
#pragma unroll
        for (int u = 0; u < 4; ++u) {
            float4 xx = xq[u];
            float4 q  = qq[u];
            float dx = q.x - xx.x, dy = q.y - xx.y, dz = q.z - xx.z, dw = q.w - xx.w;
            oq[u] = make_float4(xx.x + dx, xx.y + dy, xx.z + dz, xx.w + dw);
            ps += dx * dx + dy * dy + dz * dz + dw * dw;
        }
#pragma unroll
        for (int off = 32; off > 0; off >>= 1) ps += __shfl_down(ps, off, 64);
        if (lane == 0) atomicAdd(lsum, (double)ps);
    }
}

// ---------------- Kernel D: finalize loss ----------------
__global__ void finalize_kernel(const double* lsum, float* loss_out) {
    double m = *lsum / (double)QELEMS;
    *loss_out = (float)(m + 0.25 * m);  // e_latent + BETA * q_latent (same value)
}

extern "C" void kernel_launch(void* const* d_in, const int* in_sizes, int n_in,
                              void* d_out, int out_size, void* d_ws, size_t ws_size,
                              hipStream_t stream) {
    const float* X = (const float*)d_in[0];   // [64,32,32,64] = 4194304 floats
    const float* E = (const float*)d_in[1];   // [64,1024]     = 65536 floats

    float* out = (float*)d_out;
    float* quant = out;                  // [0, 4194304)
    float* loss  = out + QELEMS;         // [4194304]
    float* idxf  = out + QELEMS + 1;     // [4194305, ...)

    char* ws = (char*)d_ws;
    float*  Et   = (float*)(ws);             // 256 KiB
    float*  esq  = (float*)(ws + 262144);    // 4 KiB
    double* lsum = (double*)(ws + 266240);   // 8 B

    prep_kernel<<<4, 256, 0, stream>>>(E, Et, esq, lsum);
    main_kernel<<<NROWS / 64, 256, 0, stream>>>(X, Et, esq, quant, idxf, lsum);
    finalize_kernel<<<1, 1, 0, stream>>>(lsum, loss);
}

// Round 3
// 240.394 us; speedup vs baseline: 4.1371x; 2.4372x over previous
//
#include <hip/hip_runtime.h>
#include <math.h>

#define EMB_D 64
#define EMB_K 1024
#define NROWS 65536            // 64*32*32
#define QELEMS (NROWS * EMB_D) // 4194304

// d_out layout (floats): [0, 4194304) quantized | [4194304] loss | [4194305, ...) indices (as float)
// d_ws layout (bytes):   [0, 262144) Et float[1024][64] | [262144, 266240) esq float[1024]
//                        [266240, 266248) double loss accumulator

// ---------------- Kernel A: transpose codebook, per-code ||e||^2, zero loss accum ----------------
__global__ __launch_bounds__(256) void prep_kernel(const float* __restrict__ E,
                                                   float* __restrict__ Et,
                                                   float* __restrict__ esq,
                                                   double* lsum) {
    int k = blockIdx.x * 256 + threadIdx.x;
    if (k == 0) *lsum = 0.0;  // ws is re-poisoned 0xAA before every launch
    if (k >= EMB_K) return;
    float s = 0.f;
#pragma unroll
    for (int d = 0; d < EMB_D; ++d) {
        float v = E[d * EMB_K + k];       // coalesced read across k
        Et[k * EMB_D + d] = v;            // contiguous per-thread write
        s = fmaf(v, v, s);                // same chain order as round-1 (d ascending)
    }
    esq[k] = s;
}

// accumulate 4 products into acc, in x/y/z/w order (matches round-1's i-ascending chain)
#define DOT4(acc, q, e)                                    \
    do {                                                   \
        acc = fmaf((q).x, (e).x, acc);                     \
        acc = fmaf((q).y, (e).y, acc);                     \
        acc = fmaf((q).z, (e).z, acc);                     \
        acc = fmaf((q).w, (e).w, acc);                     \
    } while (0)

// ---------------- Kernel B: fused argmin + quantize + loss ----------------
// Block = 4 waves over the SAME 64 rows; wave w scans codes [w*256, w*256+256).
// k0 comes from readfirstlane -> compiler-provable wave-uniform -> codebook and
// esq reads become SCALAR loads (SMEM pipe), inner loop is v_fmac v,s,v only.
// An asm memory barrier pins the 16 x-row float4s in VGPRs (no re-load sinking).
__global__ __launch_bounds__(256, 4) void main_kernel(const float* __restrict__ X,
                                                      const float* __restrict__ Et,
                                                      const float* __restrict__ esq,
                                                      float* __restrict__ quant,
                                                      float* __restrict__ idxf,
                                                      double* lsum) {
    __shared__ float sd[4][64];
    __shared__ int   si[4][64];
    __shared__ int   sidx[64];

    const int lane = threadIdx.x & 63;
    const int w    = threadIdx.x >> 6;
    const int rowbase = blockIdx.x * 64;

    // ---- load this lane's row into 16 explicit float4 registers ----
    const float4* xr = reinterpret_cast<const float4*>(X + (size_t)(rowbase + lane) * EMB_D);
    float4 x0 = xr[0],  x1 = xr[1],  x2 = xr[2],  x3 = xr[3];
    float4 x4 = xr[4],  x5 = xr[5],  x6 = xr[6],  x7 = xr[7];
    float4 x8 = xr[8],  x9 = xr[9],  x10 = xr[10], x11 = xr[11];
    float4 x12 = xr[12], x13 = xr[13], x14 = xr[14], x15 = xr[15];

    float xsq = 0.f;
    DOT4(xsq, x0, x0);   DOT4(xsq, x1, x1);   DOT4(xsq, x2, x2);   DOT4(xsq, x3, x3);
    DOT4(xsq, x4, x4);   DOT4(xsq, x5, x5);   DOT4(xsq, x6, x6);   DOT4(xsq, x7, x7);
    DOT4(xsq, x8, x8);   DOT4(xsq, x9, x9);   DOT4(xsq, x10, x10); DOT4(xsq, x11, x11);
    DOT4(xsq, x12, x12); DOT4(xsq, x13, x13); DOT4(xsq, x14, x14); DOT4(xsq, x15, x15);

    // Pin x0..x15 in VGPRs: loads must complete before this point and cannot
    // be legally re-issued after it.
    asm volatile("" ::: "memory");

    // wave-uniform code-chunk base (readfirstlane => known-uniform => s_load)
    const int k0 = __builtin_amdgcn_readfirstlane(w) * (EMB_K / 4);

    float bestd = INFINITY;
    int   besti = 0;
    for (int k = k0; k < k0 + EMB_K / 4; k += 2) {   // 2 codes in flight (2 FMA chains)
        const float4* e0 = reinterpret_cast<const float4*>(Et + (size_t)k * EMB_D);
        const float4* e1 = e0 + 16;
        float d0 = 0.f, d1 = 0.f;
#define STEP(i) { float4 a = e0[i]; float4 b = e1[i]; DOT4(d0, x##i, a); DOT4(d1, x##i, b); }
        STEP(0)  STEP(1)  STEP(2)  STEP(3)
        STEP(4)  STEP(5)  STEP(6)  STEP(7)
        STEP(8)  STEP(9)  STEP(10) STEP(11)
        STEP(12) STEP(13) STEP(14) STEP(15)
#undef STEP
        float dist0 = (xsq - 2.0f * d0) + esq[k];
        float dist1 = (xsq - 2.0f * d1) + esq[k + 1];
        if (dist0 < bestd) { bestd = dist0; besti = k; }
        if (dist1 < bestd) { bestd = dist1; besti = k + 1; }
    }
    sd[w][lane] = bestd;
    si[w][lane] = besti;
    __syncthreads();

    // ---- combine the 4 k-chunks (ascending w keeps lowest index on ties) ----
    if (threadIdx.x < 64) {
        float bd = sd[0][lane];
        int   bi = si[0][lane];
#pragma unroll
        for (int u = 1; u < 4; ++u) {
            if (sd[u][lane] < bd) { bd = sd[u][lane]; bi = si[u][lane]; }
        }
        sidx[lane] = bi;
        idxf[rowbase + lane] = (float)bi;
    }
    __syncthreads();

    // ---- fused quantize + loss: thread t handles row t>>2, quarter t&3 (coalesced) ----
    {
        const int r = threadIdx.x >> 2;
        const int p = threadIdx.x & 3;
        const int k = sidx[r];
        const float4* xq = reinterpret_cast<const float4*>(X + (size_t)(rowbase + r) * EMB_D) + p * 4;
        const float4* qq = reinterpret_cast<const float4*>(Et + (size_t)k * EMB_D) + p * 4;
        float4*       oq = reinterpret_cast<float4*>(quant + (size_t)(rowbase + r) * EMB_D) + p * 4;
        float ps = 0.f;
#pragma unroll
        for (int u = 0; u < 4; ++u) {
            float4 xx = xq[u];
            float4 q  = qq[u];
            float dx = q.x - xx.x, dy = q.y - xx.y, dz = q.z - xx.z, dw = q.w - xx.w;
            oq[u] = make_float4(xx.x + dx, xx.y + dy, xx.z + dz, xx.w + dw);
            ps += dx * dx + dy * dy + dz * dz + dw * dw;
        }
#pragma unroll
        for (int off = 32; off > 0; off >>= 1) ps += __shfl_down(ps, off, 64);
        if (lane == 0) atomicAdd(lsum, (double)ps);
    }
}

// ---------------- Kernel D: finalize loss ----------------
__global__ void finalize_kernel(const double* lsum, float* loss_out) {
    double m = *lsum / (double)QELEMS;
    *loss_out = (float)(m + 0.25 * m);  // e_latent + BETA * q_latent (same value)
}

extern "C" void kernel_launch(void* const* d_in, const int* in_sizes, int n_in,
                              void* d_out, int out_size, void* d_ws, size_t ws_size,
                              hipStream_t stream) {
    const float* X = (const float*)d_in[0];   // [64,32,32,64] = 4194304 floats
    const float* E = (const float*)d_in[1];   // [64,1024]     = 65536 floats

    float* out = (float*)d_out;
    float* quant = out;                  // [0, 4194304)
    float* loss  = out + QELEMS;         // [4194304]
    float* idxf  = out + QELEMS + 1;     // [4194305, ...)

    char* ws = (char*)d_ws;
    float*  Et   = (float*)(ws);             // 256 KiB
    float*  esq  = (float*)(ws + 262144);    // 4 KiB
    double* lsum = (double*)(ws + 266240);   // 8 B

    prep_kernel<<<4, 256, 0, stream>>>(E, Et, esq, lsum);
    main_kernel<<<NROWS / 64, 256, 0, stream>>>(X, Et, esq, quant, idxf, lsum);
    finalize_kernel<<<1, 1, 0, stream>>>(lsum, loss);
}